// Round 7
// baseline (606.743 us; speedup 1.0000x reference)
//
#include <hip/hip_runtime.h>
#include <math.h>

#define TT 2048
#define BB 32
#define EE 512
#define NN 512

typedef short bf16x8 __attribute__((ext_vector_type(8)));
typedef float f32x4 __attribute__((ext_vector_type(4)));

__device__ __forceinline__ short bf16_rne(float x) {
    const unsigned u = __float_as_uint(x);
    return (short)((u + 0x7FFFu + ((u >> 16) & 1u)) >> 16);
}
__device__ __forceinline__ float bf16_f32(short h) {
    return __uint_as_float(((unsigned)(unsigned short)h) << 16);
}

// ---------------------------------------------------------------------------
// padding_mask dtype detector: int32 0/1 words stay <=1; byte-bool rows are
// monotonic so any packed word is 0x01000000/0x01010000/0x01010101/... (>1).
__global__ void detect_mask_kernel(const unsigned* __restrict__ pm, int* __restrict__ flag) {
    __shared__ int s[1024];
    const int l = threadIdx.x;
    int bad = 0;
    for (int i = l; i < BB * TT; i += 1024) bad |= (pm[i] > 1u);
    s[l] = bad;
    __syncthreads();
    for (int st = 512; st > 0; st >>= 1) { if (l < st) s[l] |= s[l + st]; __syncthreads(); }
    if (l == 0) *flag = s[0];
}

__device__ __forceinline__ int pad_at(const void* pm, int idx, int isByte) {
    return isByte ? (int)(((const unsigned char*)pm)[idx] != 0)
                  : (int)(((const int*)pm)[idx] != 0);
}

// ---------------------------------------------------------------------------
// padding_start[b] = count of not-pad = lengths[b]
__global__ void compute_ps_kernel(const void* __restrict__ pm, const int* __restrict__ flag,
                                  int* __restrict__ ps) {
    __shared__ int s[256];
    const int b = blockIdx.x, l = threadIdx.x;
    const int isByte = *flag;
    int cnt = 0;
    for (int t = l; t < TT; t += 256) cnt += (pad_at(pm, b * TT + t, isByte) == 0);
    s[l] = cnt;
    __syncthreads();
    for (int st = 128; st > 0; st >>= 1) { if (l < st) s[l] += s[l + st]; __syncthreads(); }
    if (l == 0) ps[b] = s[0];
}

// ---------------------------------------------------------------------------
// One-time W split+transpose: W[E][N] fp32 -> Wh/Wl[N][E] bf16 (k contiguous),
// RNE hi + RNE residual lo. Scratch lives in out_cif (overwritten later).
__global__ __launch_bounds__(256) void split_w_kernel(const float* __restrict__ W,
                                                      short* __restrict__ Wh,
                                                      short* __restrict__ Wl) {
    __shared__ float tile[32][33];
    const int bn = blockIdx.x, bk = blockIdx.y;
    const int tx = threadIdx.x & 31, ty = threadIdx.x >> 5;
    for (int i = ty; i < 32; i += 8)
        tile[i][tx] = W[(size_t)(bk * 32 + i) * NN + bn * 32 + tx];
    __syncthreads();
    for (int i = ty; i < 32; i += 8) {
        const float val = tile[tx][i];
        const short h = bf16_rne(val);
        const short lo = bf16_rne(val - bf16_f32(h));
        const size_t o = (size_t)(bn * 32 + i) * EE + bk * 32 + tx;
        Wh[o] = h;
        Wl[o] = lo;
    }
}

// ---------------------------------------------------------------------------
// GEMM v7: x read & converted ONCE (nc loop moved inside K-loop).
// 512 threads = 8 waves (2M x 4N); tile 128 rows x 512 cols; BK=64.
// acc[2][4][4] f32x4 (128 VGPR), all-static indexing.
// A: reg-load fp32 (T14 next-tile prefetch) -> RNE split -> swizzled
//    ds_write_b128 (conflict-free: 8-lane phase covers 8 distinct slots).
// B: fragments loaded straight from global Wh/Wl (1 MB, L2-resident) -> no
//    B-LDS, no B staging barriers. LDS 38 KB; 16 barriers total.
__global__ __launch_bounds__(512, 2) void gemm_weight_mfma(
    const float* __restrict__ x, const void* __restrict__ pm, const int* __restrict__ flag,
    const short* __restrict__ Wh, const short* __restrict__ Wl,
    const float* __restrict__ bias, const float* __restrict__ v, const float* __restrict__ vb,
    float* __restrict__ weight_bt) {
    __shared__ __align__(16) short Ah[128 * 64];
    __shared__ __align__(16) short Al[128 * 64];
    __shared__ float bias_s[512], v_s[512];
    __shared__ float lsum[128][4];

    const int tid = threadIdx.x;
    const int l = tid & 63, wid = tid >> 6;
    const int wr = wid >> 2, wc = wid & 3;          // 2M x 4N waves
    const int q = l >> 4, li = l & 15, x7 = l & 7;
    const int tp = blockIdx.x;

    bias_s[tid < 512 ? tid : 0] = bias[tid < 512 ? tid : 0];
    v_s[tid < 512 ? tid : 0] = v[tid < 512 ? tid : 0];

    const float* xblk = x + (size_t)tp * 128 * EE;
    // A staging: 4 threads per row, 16 contiguous k each (2 chunks of 8)
    const int arow = tid >> 2;
    const int kseg = (tid & 3) << 4;                // 0,16,32,48
    const int c0 = (tid & 3) << 1;                  // chunk base 0,2,4,6
    const int aswz = arow & 7;

    f32x4 acc[2][4][4];
#pragma unroll
    for (int nc = 0; nc < 2; ++nc)
#pragma unroll
        for (int m = 0; m < 4; ++m)
#pragma unroll
            for (int n = 0; n < 4; ++n) acc[nc][m][n] = (f32x4){0.f, 0.f, 0.f, 0.f};

    // prologue: prefetch first A sub-tile to regs
    float4 p0, p1, p2, p3;
    {
        const float* xr = xblk + (size_t)arow * EE + kseg;
        p0 = *(const float4*)&xr[0];
        p1 = *(const float4*)&xr[4];
        p2 = *(const float4*)&xr[8];
        p3 = *(const float4*)&xr[12];
    }

    for (int ks = 0; ks < 8; ++ks) {
        const int k0 = ks * 64;
        float e[16];
        *(float4*)&e[0]  = p0; *(float4*)&e[4]  = p1;
        *(float4*)&e[8]  = p2; *(float4*)&e[12] = p3;
        if (ks < 7) {                                // issue next-tile loads now;
            const float* xr = xblk + (size_t)arow * EE + (k0 + 64) + kseg;
            p0 = *(const float4*)&xr[0];             // they drain under the MFMA
            p1 = *(const float4*)&xr[4];             // phase below (T14)
            p2 = *(const float4*)&xr[8];
            p3 = *(const float4*)&xr[12];
        }
        // convert + swizzled LDS write (2 chunks x h/l)
        bf16x8 hv0, lv0, hv1, lv1;
#pragma unroll
        for (int j = 0; j < 8; ++j) {
            const short h = bf16_rne(e[j]);
            hv0[j] = h;
            lv0[j] = bf16_rne(e[j] - bf16_f32(h));
        }
#pragma unroll
        for (int j = 0; j < 8; ++j) {
            const short h = bf16_rne(e[8 + j]);
            hv1[j] = h;
            lv1[j] = bf16_rne(e[8 + j] - bf16_f32(h));
        }
        const int pa = arow * 64 + (((c0 + 0) ^ aswz) << 3);
        const int pb = arow * 64 + (((c0 + 1) ^ aswz) << 3);
        *(bf16x8*)&Ah[pa] = hv0; *(bf16x8*)&Al[pa] = lv0;
        *(bf16x8*)&Ah[pb] = hv1; *(bf16x8*)&Al[pb] = lv1;
        __syncthreads();
        // compute: 2 kf x (2 nc x 4 n x 4 m) x 3 terms = 192 MFMA / wave
#pragma unroll
        for (int kf = 0; kf < 2; ++kf) {
            const int co = (((kf << 2) + q) ^ x7) << 3;
            bf16x8 ah[4], al[4];
#pragma unroll
            for (int m = 0; m < 4; ++m) {
                const int ro = (wr * 64 + m * 16 + li) * 64 + co;
                ah[m] = *(const bf16x8*)&Ah[ro];
                al[m] = *(const bf16x8*)&Al[ro];
            }
            const int kk = k0 + (kf << 5) + (q << 3);
#pragma unroll
            for (int nc = 0; nc < 2; ++nc) {
#pragma unroll
                for (int n = 0; n < 4; ++n) {
                    const int col = nc * 256 + wc * 64 + n * 16 + li;
                    const size_t ga = (size_t)col * EE + kk;
                    const bf16x8 bh = *(const bf16x8*)&Wh[ga];
                    const bf16x8 bl = *(const bf16x8*)&Wl[ga];
#pragma unroll
                    for (int m = 0; m < 4; ++m) {
                        acc[nc][m][n] = __builtin_amdgcn_mfma_f32_16x16x32_bf16(ah[m], bh, acc[nc][m][n], 0, 0, 0);
                        acc[nc][m][n] = __builtin_amdgcn_mfma_f32_16x16x32_bf16(al[m], bh, acc[nc][m][n], 0, 0, 0);
                        acc[nc][m][n] = __builtin_amdgcn_mfma_f32_16x16x32_bf16(ah[m], bl, acc[nc][m][n], 0, 0, 0);
                    }
                }
            }
        }
        __syncthreads();                             // LDS free for next stage
    }
    // epilogue: relu + dot(v) per col, per-row partials over this lane's 8 cols
    float rowsum[4][4];
#pragma unroll
    for (int m = 0; m < 4; ++m)
#pragma unroll
        for (int r = 0; r < 4; ++r) rowsum[m][r] = 0.f;
#pragma unroll
    for (int nc = 0; nc < 2; ++nc)
#pragma unroll
        for (int m = 0; m < 4; ++m)
#pragma unroll
            for (int n = 0; n < 4; ++n) {
                const int col = nc * 256 + wc * 64 + n * 16 + li;
                const float bcol = bias_s[col], vcol = v_s[col];
#pragma unroll
                for (int r = 0; r < 4; ++r) {
                    const float h = fmaxf(acc[nc][m][n][r] + bcol, 0.f);
                    rowsum[m][r] = fmaf(h, vcol, rowsum[m][r]);
                }
            }
    // reduce over the 16 lanes (li) sharing each row-group
#pragma unroll
    for (int m = 0; m < 4; ++m)
#pragma unroll
        for (int r = 0; r < 4; ++r) {
            float s = rowsum[m][r];
            s += __shfl_xor(s, 1, 64);
            s += __shfl_xor(s, 2, 64);
            s += __shfl_xor(s, 4, 64);
            s += __shfl_xor(s, 8, 64);
            rowsum[m][r] = s;
        }
    if (li == 0) {
#pragma unroll
        for (int m = 0; m < 4; ++m)
#pragma unroll
            for (int r = 0; r < 4; ++r)
                lsum[wr * 64 + m * 16 + q * 4 + r][wc] = rowsum[m][r];
    }
    __syncthreads();
    if (tid < 128) {
        const int isByte = *flag;
        const float logit = ((lsum[tid][0] + lsum[tid][1]) +
                             (lsum[tid][2] + lsum[tid][3])) + *vb;   // fixed order
        const float wg = 1.0f / (1.0f + expf(-logit));
        const int gr = tp * 128 + tid;
        const int t = gr >> 5, b = gr & 31;
        weight_bt[(size_t)b * TT + t] = pad_at(pm, b * TT + t, isByte) ? 0.f : wg;
    }
}

// ---------------------------------------------------------------------------
// Scan v5 (serial half): minimal serial core + BATCHED band rescue.
// (unchanged, passed r6)
#define BAND 5e-5f
#define MAXEV 32
__global__ __launch_bounds__(64) void cif_scan_kernel(
    float* __restrict__ weight_bt,
    const float* __restrict__ x, const float* __restrict__ W,
    const float* __restrict__ bias, const float* __restrict__ v,
    const float* __restrict__ vb,
    float* __restrict__ cseq_g) {
    __shared__ __align__(16) float wsm[TT];
    __shared__ __align__(16) float cseq[TT];
    __shared__ __align__(16) float xrow[EE];
    __shared__ int evl_s[MAXEV];
    __shared__ float wfix_s[MAXEV];
    __shared__ unsigned fixedbm[TT / 32];
    const int b = blockIdx.x, l = threadIdx.x;
    float* wrow = weight_bt + (size_t)b * TT;

    for (int t = l * 8; t < TT; t += 64 * 8) {
        *(float4*)&wsm[t]     = *(const float4*)&wrow[t];
        *(float4*)&wsm[t + 4] = *(const float4*)&wrow[t + 4];
    }
    fixedbm[l] = 0u;
    __syncthreads();

    int t0s = 0;
    for (int iter = 0; iter < 64; ++iter) {
        if (l == 0) {
            float c = (t0s > 0) ? cseq[t0s - 1] : 0.f;
            float4 n1a = *(const float4*)&wsm[t0s];
            float4 n1b = *(const float4*)&wsm[t0s + 4];
            const int tp8 = (t0s + 8) & (TT - 1);
            float4 n2a = *(const float4*)&wsm[tp8];
            float4 n2b = *(const float4*)&wsm[tp8 + 4];
            for (int t = t0s; t < TT; t += 8) {
                const float4 wa = n1a, wb = n1b;
                n1a = n2a; n1b = n2b;
                const int tn = (t + 16) & (TT - 1);
                n2a = *(const float4*)&wsm[tn];
                n2b = *(const float4*)&wsm[tn + 4];
                const float wv[8] = {wa.x, wa.y, wa.z, wa.w, wb.x, wb.y, wb.z, wb.w};
                float cs[8];
#pragma unroll
                for (int u = 0; u < 8; ++u) {
                    const float w = wv[u];
                    const float a = 1.0f - c;
                    const float s = c + w;
                    const float bb = w - a;
                    c = (s >= 1.0f) ? bb : s;
                    cs[u] = c;
                }
                *(float4*)&cseq[t]     = make_float4(cs[0], cs[1], cs[2], cs[3]);
                *(float4*)&cseq[t + 4] = make_float4(cs[4], cs[5], cs[6], cs[7]);
            }
        }
        __syncthreads();
        const int base = l * 32;
        const unsigned fixw = fixedbm[l];
        unsigned hm = 0u;
        for (int u = 0; u < 32; ++u) {
            const int t = base + u;
            const float w = wsm[t];
            if (w > 0.f && !((fixw >> u) & 1u)) {
                const float cprev = t ? cseq[t - 1] : 0.f;
                if (fabsf(cprev + w - 1.0f) < BAND) hm |= (1u << u);
            }
        }
        unsigned long long bal = __ballot(hm != 0u);
        int nev = 0;
        while (bal != 0ull && nev < MAXEV) {
            const int src = __ffsll((unsigned long long)bal) - 1;
            unsigned hs = __shfl(hm, src, 64);
            while (hs != 0u && nev < MAXEV) {
                const int u = __ffs(hs) - 1;
                if (l == 0) evl_s[nev] = src * 32 + u;
                ++nev;
                hs &= hs - 1u;
            }
            bal &= bal - 1ull;
        }
        __syncthreads();
        if (nev == 0) break;
        const float4 v0 = *(const float4*)&v[l * 8];
        const float4 v1 = *(const float4*)&v[l * 8 + 4];
        const float4 bi0 = *(const float4*)&bias[l * 8];
        const float4 bi1 = *(const float4*)&bias[l * 8 + 4];
        for (int k = 0; k < nev; ++k) {
            const int ev = evl_s[k];
            const float* xr = &x[((size_t)ev * BB + b) * EE];
            *(float4*)&xrow[l * 8]     = *(const float4*)&xr[l * 8];
            *(float4*)&xrow[l * 8 + 4] = *(const float4*)&xr[l * 8 + 4];
            __syncthreads();
            float h[8] = {bi0.x, bi0.y, bi0.z, bi0.w, bi1.x, bi1.y, bi1.z, bi1.w};
#pragma unroll 4
            for (int e = 0; e < EE; ++e) {
                const float xe = xrow[e];
                const float4 w0 = *(const float4*)&W[(size_t)e * NN + l * 8];
                const float4 w1 = *(const float4*)&W[(size_t)e * NN + l * 8 + 4];
                h[0] = fmaf(xe, w0.x, h[0]); h[1] = fmaf(xe, w0.y, h[1]);
                h[2] = fmaf(xe, w0.z, h[2]); h[3] = fmaf(xe, w0.w, h[3]);
                h[4] = fmaf(xe, w1.x, h[4]); h[5] = fmaf(xe, w1.y, h[5]);
                h[6] = fmaf(xe, w1.z, h[6]); h[7] = fmaf(xe, w1.w, h[7]);
            }
            float part = fmaxf(h[0], 0.f) * v0.x;
            part = fmaf(fmaxf(h[1], 0.f), v0.y, part);
            part = fmaf(fmaxf(h[2], 0.f), v0.z, part);
            part = fmaf(fmaxf(h[3], 0.f), v0.w, part);
            part = fmaf(fmaxf(h[4], 0.f), v1.x, part);
            part = fmaf(fmaxf(h[5], 0.f), v1.y, part);
            part = fmaf(fmaxf(h[6], 0.f), v1.z, part);
            part = fmaf(fmaxf(h[7], 0.f), v1.w, part);
#pragma unroll
            for (int s = 32; s >= 1; s >>= 1) part += __shfl_xor(part, s, 64);
            if (l == 0) wfix_s[k] = 1.0f / (1.0f + expf(-(part + *vb)));
            __syncthreads();
        }
        int firstflip = -1;
        for (int k = 0; k < nev; ++k) {
            const int ev = evl_s[k];
            const float wnew = wfix_s[k];
            const float cprev = ev ? cseq[ev - 1] : 0.f;
            const bool of = (cprev + wsm[ev]) >= 1.0f;
            const bool nf = (cprev + wnew) >= 1.0f;
            if (l == 0) {
                wsm[ev] = wnew;
                wrow[ev] = wnew;
                fixedbm[ev >> 5] |= (1u << (ev & 31));
            }
            if (nf != of && firstflip < 0) firstflip = ev;
        }
        __syncthreads();
        if (firstflip < 0) break;
        t0s = firstflip & ~7;
    }
    __syncthreads();
    for (int t = l * 8; t < TT; t += 64 * 8) {
        *(float4*)&cseq_g[(size_t)b * TT + t]     = *(const float4*)&cseq[t];
        *(float4*)&cseq_g[(size_t)b * TT + t + 4] = *(const float4*)&cseq[t + 4];
    }
}

// ---------------------------------------------------------------------------
// Scan v5 (parallel half): P1-P4 derivation. (unchanged, passed r6)
__global__ __launch_bounds__(64) void cif_derive_kernel(
    const float* __restrict__ weight_bt, const float* __restrict__ cseq_g,
    const int* __restrict__ ps_arr,
    float* __restrict__ cc_bt, float4* __restrict__ recs,
    int* __restrict__ nfr, float* __restrict__ out_q, float* __restrict__ out_marks) {
    __shared__ __align__(16) float wsm[TT];
    __shared__ __align__(16) float cseq[TT];
    const int b = blockIdx.x, l = threadIdx.x;
    const int ps = ps_arr[b];
    for (int t = l * 8; t < TT; t += 64 * 8) {
        *(float4*)&wsm[t]      = *(const float4*)&weight_bt[(size_t)b * TT + t];
        *(float4*)&wsm[t + 4]  = *(const float4*)&weight_bt[(size_t)b * TT + t + 4];
        *(float4*)&cseq[t]     = *(const float4*)&cseq_g[(size_t)b * TT + t];
        *(float4*)&cseq[t + 4] = *(const float4*)&cseq_g[(size_t)b * TT + t + 4];
    }
    __syncthreads();

    const int base = l * 32;
    unsigned fmask = 0u;
    for (int u = 0; u < 32; ++u) {
        const int t = base + u;
        const float cprev = t ? cseq[t - 1] : 0.f;
        if (cprev + wsm[t] >= 1.0f) fmask |= (1u << u);
    }
    const int myF = __popc(fmask);
    int myLast = fmask ? (base + (31 - __clz(fmask))) : -1;

    int inc = myF;
#pragma unroll
    for (int off = 1; off < 64; off <<= 1) {
        const int n = __shfl_up(inc, off, 64);
        if (l >= off) inc += n;
    }
    const int exF = inc - myF;
    const int totF = __shfl(inc, 63, 64);
    int incLast = myLast;
#pragma unroll
    for (int off = 1; off < 64; off <<= 1) {
        const int n = __shfl_up(incLast, off, 64);
        if (l >= off) incLast = (incLast > n) ? incLast : n;
    }
    int prevFire = __shfl_up(incLast, 1, 64);
    if (l == 0) prevFire = -1;
    int tf = (prevFire > 0) ? prevFire : 0;

    int slot = exF;
    int tailWrote = 0;
    for (int u = 0; u < 32; ++u) {
        const int t = base + u;
        if (fmask & (1u << u)) {
            recs[(size_t)b * TT + slot] =
                make_float4(__int_as_float(tf), __int_as_float(t), cseq[tf], 1.0f);
            ++slot;
            tf = t;
        }
        if (t == ps) {
            const float cw = cseq[t];
            if (cw > 0.6f && totF < TT) {
                recs[(size_t)b * TT + totF] =
                    make_float4(__int_as_float(tf), __int_as_float(t - 1), cseq[tf],
                                1.0f / (cw + 1e-10f));
                tailWrote = 1;
            }
        }
    }
    const int tailAny = (__ballot(tailWrote) != 0ull) ? 1 : 0;

    float qpart = 0.f;
    for (int t = l; t < TT; t += 64) {
        const float w = wsm[t];
        const float cprev = t ? cseq[t - 1] : 0.f;
        const bool fired = (cprev + w) >= 1.0f;
        const float cc = fired ? (1.0f - cprev) : w;
        const bool tail = (t == ps) && (cseq[t] > 0.6f);
        cc_bt[(size_t)b * TT + t] = cc;
        out_marks[(size_t)b * TT + t] = (fired || tail) ? 1.f : 0.f;
        qpart += w;
    }
#pragma unroll
    for (int s = 32; s >= 1; s >>= 1) qpart += __shfl_xor(qpart, s, 64);
    if (l == 0) { out_q[b] = qpart; nfr[b] = totF + tailAny; }
}

// ---------------------------------------------------------------------------
// Parallel frame materialization: block (j, b) -> compacted slot j of batch b.
__global__ __launch_bounds__(128) void cif_out_kernel(
    const float* __restrict__ x, const float* __restrict__ cc_bt,
    const float4* __restrict__ recs, const int* __restrict__ nfr,
    float* __restrict__ out_cif, float* __restrict__ out_mask) {
    const int j = blockIdx.x, b = blockIdx.y;
    const int l = threadIdx.x;
    const int m = nfr[b];
    float4 acc = make_float4(0.f, 0.f, 0.f, 0.f);
    const size_t obase = ((size_t)b * TT + j) * EE + l * 4;
    if (j < m) {
        const float4 r = recs[b * TT + j];
        const int t0 = __float_as_int(r.x);
        const int t1 = __float_as_int(r.y);
        const float fcoef = r.z, scale = r.w;
        for (int t = t0; t <= t1; ++t) {
            const float coeff = (t == t0) ? fcoef : cc_bt[(size_t)b * TT + t];
            const float4 xv = *(const float4*)&x[((size_t)t * BB + b) * EE + l * 4];
            acc.x = fmaf(coeff, xv.x, acc.x);
            acc.y = fmaf(coeff, xv.y, acc.y);
            acc.z = fmaf(coeff, xv.z, acc.z);
            acc.w = fmaf(coeff, xv.w, acc.w);
        }
        acc.x *= scale; acc.y *= scale; acc.z *= scale; acc.w *= scale;
        if (l == 0) out_mask[b * TT + j] = 1.f;
    } else {
        if (l == 0) out_mask[b * TT + j] = 0.f;
    }
    *(float4*)&out_cif[obase] = acc;
}

// ---------------------------------------------------------------------------
extern "C" void kernel_launch(void* const* d_in, const int* in_sizes, int n_in,
                              void* d_out, int out_size, void* d_ws, size_t ws_size,
                              hipStream_t stream) {
    const float* x    = (const float*)d_in[0];   // (T, B, E)
    const void*  pm   = d_in[1];                 // (B, T) bool -> int32 or bytes (detected)
    const float* W    = (const float*)d_in[2];   // (E, N)
    const float* bias = (const float*)d_in[3];   // (N,)
    const float* v    = (const float*)d_in[4];   // (N, 1)
    const float* vb   = (const float*)d_in[5];   // (1,)

    // workspace: same footprint class as the proven round-0 kernel (~1.5 MB)
    float* ws        = (float*)d_ws;
    float* weight_bt = ws;                                 // BB*TT
    float* cc_bt     = ws + (size_t)TT * BB;               // BB*TT
    float4* recs     = (float4*)(ws + 2 * (size_t)TT * BB);// BB*TT float4
    int* nfr         = (int*)(ws + 2 * (size_t)TT * BB + 4 * (size_t)BB * TT);
    int* ps          = nfr + BB;
    int* flag        = ps + BB;

    float* out_cif   = (float*)d_out;                     // (B, T, E)
    float* out_mask  = out_cif + (size_t)BB * TT * EE;    // (B, T)
    float* out_q     = out_mask + (size_t)BB * TT;        // (B,)
    float* out_marks = out_q + BB;                        // (B, T)

    // Scratch inside out_cif (128 MB, fully overwritten by cif_out_kernel):
    // [0, 1MB): Wh/Wl bf16 split; [2MB, 2.25MB): cseq dump. Stream-ordered.
    short* Whs    = (short*)out_cif;                      // 512 KB
    short* Wls    = Whs + (size_t)NN * EE;                // 512 KB
    float* cseq_g = (float*)((char*)out_cif + (2u << 20));// 256 KB

    detect_mask_kernel<<<1, 1024, 0, stream>>>((const unsigned*)pm, flag);
    compute_ps_kernel<<<BB, 256, 0, stream>>>(pm, flag, ps);
    split_w_kernel<<<dim3(16, 16), 256, 0, stream>>>(W, Whs, Wls);
    gemm_weight_mfma<<<512, 512, 0, stream>>>(x, pm, flag, Whs, Wls, bias, v, vb, weight_bt);
    cif_scan_kernel<<<BB, 64, 0, stream>>>(weight_bt, x, W, bias, v, vb, cseq_g);
    cif_derive_kernel<<<BB, 64, 0, stream>>>(weight_bt, cseq_g, ps, cc_bt, recs,
                                             nfr, out_q, out_marks);
    cif_out_kernel<<<dim3(TT, BB), 128, 0, stream>>>(x, cc_bt, recs, nfr, out_cif, out_mask);
}